// Round 1
// baseline (6815.158 us; speedup 1.0000x reference)
//
#include <hip/hip_runtime.h>
#include <cmath>

#define T_STEPS 128
#define B_SZ    4
#define L_DIM   6368
#define L4V     1592      // L_DIM/4
#define KH      3184      // half of k-dim staged in LDS
#define KH4     796       // KH/4
#define H1_DIM  2133
#define H2_DIM  4250
#define NBLK    256
#define NMV     255
#define NPAIR   3184      // L_DIM/2 row-pairs

// ws layout (float offsets)
#define OFF_THA  0
#define OFF_THB  25472
#define OFF_W1T  50944     // 2 slots * 16384
#define OFF_W2T  83712     // 2 slots * 8192
#define OFF_DIFF 100096    // 2 slots * 68
#define OFF_BAR  100232    // 1 (unsigned)
#define OFF_H1   100236    // 4*2133
#define OFF_H2   108768    // 4*4250  (end: 125768 floats = 503 KB)

__device__ inline void fma4(float4& acc, float4 a, float4 t0, float4 t1, float4 t2, float4 t3) {
    acc.x += a.x*t0.x + a.y*t1.x + a.z*t2.x + a.w*t3.x;
    acc.y += a.x*t0.y + a.y*t1.y + a.z*t2.y + a.w*t3.y;
    acc.z += a.x*t0.z + a.y*t1.z + a.z*t2.z + a.w*t3.z;
    acc.w += a.x*t0.w + a.y*t1.w + a.z*t2.w + a.w*t3.w;
}

__device__ inline float4 red4(float4 v) {
    #pragma unroll
    for (int off = 32; off; off >>= 1) {
        v.x += __shfl_xor(v.x, off);
        v.y += __shfl_xor(v.y, off);
        v.z += __shfl_xor(v.z, off);
        v.w += __shfl_xor(v.w, off);
    }
    return v;
}

__device__ inline float4 bminit(const float* __restrict__ Bm, const float* __restrict__ dvec,
                                int r, int l) {
    float4 a = make_float4(0.f, 0.f, 0.f, 0.f);
    if (l < 17) {
        float bv = Bm[r*17 + l];
        a.x = bv * dvec[l];
        a.y = bv * dvec[17 + l];
        a.z = bv * dvec[34 + l];
        a.w = bv * dvec[51 + l];
    }
    return a;
}

// scatter w1/w2 regions of theta' transposed for the root MLP's coalesced reads
__device__ inline void aux_write(float4* w1o, float4* w2o, int r, float4 v) {
    if (r >= 128 && r < 4224) {
        int j = r - 128;                   // j = r_mlp*64 + k
        w1o[(j & 63)*64 + (j >> 6)] = v;   // [k][r_mlp] x 4 batches
    } else if (r >= 4288 && r < 6336) {
        int j = r - 4288;
        w2o[(j & 63)*32 + (j >> 6)] = v;
    }
}

__device__ inline float softplusf(float x) {
    return (x > 20.f) ? x : log1pf(expf(x));
}

__device__ inline void grid_barrier(unsigned* bar, unsigned target) {
    __syncthreads();
    if (threadIdx.x == 0) {
        __threadfence();  // release our writes device-wide
        __hip_atomic_fetch_add(bar, 1u, __ATOMIC_RELEASE, __HIP_MEMORY_SCOPE_AGENT);
        while (__hip_atomic_load(bar, __ATOMIC_ACQUIRE, __HIP_MEMORY_SCOPE_AGENT) < target) {
            __builtin_amdgcn_s_sleep(2);
        }
        __threadfence();  // acquire: invalidate caches before reading others' writes
    }
    __syncthreads();
}

__global__ __launch_bounds__(512)
void seq_kernel(const float* __restrict__ A,
                const float* __restrict__ Bm,
                const float* __restrict__ xs,
                const float* __restrict__ ts,
                float* __restrict__ outp,
                float* thetaA, float* thetaB,
                float* w1t, float* w2t, float* diffb,
                unsigned* bar)
{
    __shared__ float4 sth[KH];
    const int blk = blockIdx.x;
    const int tid = threadIdx.x;
    const int w = tid >> 6, l = tid & 63;
    const float4* A4 = (const float4*)A;

    if (blk < NMV) {
        // --------- matvec blocks ---------
        const int p0 = (blk * NPAIR) / NMV;
        const int p1 = ((blk + 1) * NPAIR) / NMV;   // 12..13 pairs per block
        const int pA = p0 + w;                       // always < p1 (>=12 pairs, 8 waves)
        const int pB = pA + 8;
        const bool hasB = pB < p1;
        const int rA = pA * 2;
        const int rB = pB * 2;

        for (int it = 0; it <= T_STEPS; ++it) {
            if (it < T_STEPS) {
                const float4* thIn4 = (const float4*)((it & 1) ? thetaB : thetaA);
                float4* thOut4 = (float4*)((it & 1) ? thetaA : thetaB);
                float4* w1o = (float4*)(w1t + ((it + 1) & 1) * 16384);
                float4* w2o = (float4*)(w2t + ((it + 1) & 1) * 8192);
                const float* dvec = diffb + (it & 1) * 68;

                float4 accA0 = bminit(Bm, dvec, rA,     l);
                float4 accA1 = bminit(Bm, dvec, rA + 1, l);
                float4 accB0 = make_float4(0.f,0.f,0.f,0.f);
                float4 accB1 = make_float4(0.f,0.f,0.f,0.f);
                if (hasB) { accB0 = bminit(Bm, dvec, rB, l); accB1 = bminit(Bm, dvec, rB + 1, l); }

                for (int h = 0; h < 2; ++h) {
                    __syncthreads();  // protect LDS from previous half / iteration
                    for (int s = tid; s < KH; s += 512) sth[s] = thIn4[h*KH + s];
                    __syncthreads();
                    const float4* a0 = A4 + (size_t)rA * L4V + h*KH4;
                    const float4* a1 = a0 + L4V;
                    const float4* c0 = A4 + (size_t)rB * L4V + h*KH4;
                    const float4* c1 = c0 + L4V;
                    for (int j = l; j < KH4; j += 64) {
                        float4 t0 = sth[4*j + 0], t1 = sth[4*j + 1];
                        float4 t2 = sth[4*j + 2], t3 = sth[4*j + 3];
                        float4 av0 = a0[j], av1 = a1[j];
                        fma4(accA0, av0, t0, t1, t2, t3);
                        fma4(accA1, av1, t0, t1, t2, t3);
                        if (hasB) {
                            float4 bv0 = c0[j], bv1 = c1[j];
                            fma4(accB0, bv0, t0, t1, t2, t3);
                            fma4(accB1, bv1, t0, t1, t2, t3);
                        }
                    }
                }
                accA0 = red4(accA0); accA1 = red4(accA1);
                if (hasB) { accB0 = red4(accB0); accB1 = red4(accB1); }
                if (l == 0) {
                    thOut4[rA]     = accA0;  aux_write(w1o, w2o, rA,     accA0);
                    thOut4[rA + 1] = accA1;  aux_write(w1o, w2o, rA + 1, accA1);
                    if (hasB) {
                        thOut4[rB]     = accB0;  aux_write(w1o, w2o, rB,     accB0);
                        thOut4[rB + 1] = accB1;  aux_write(w1o, w2o, rB + 1, accB1);
                    }
                }
            }
            if (it < T_STEPS) grid_barrier(bar, (unsigned)(NBLK * (it + 1)));
        }
    } else {
        // --------- root block: root_apply_{it-1} + prepare diff_{it+1} ---------
        const int b = w;  // waves 0..3 = batches; 4..7 idle
        for (int it = 0; it <= T_STEPS; ++it) {
            float xv = 0.f;
            if (b < B_SZ) {
                if (it >= 1) {
                    const int t = it - 1;
                    const float* th  = (it & 1) ? thetaB : thetaA;  // theta^{it}
                    const float* w1c = w1t + (it & 1) * 16384;
                    const float* w2c = w2t + (it & 1) * 8192;
                    float tcur = ts[b*T_STEPS + t];
                    float tin = (t >= 1) ? (2.f*tcur - ts[b*T_STEPS + t - 1]) : tcur;
                    // h0 = relu(w0*tin + c0)
                    float h0 = fmaxf(th[l*4 + b] * tin + th[(64 + l)*4 + b], 0.f);
                    // h1 = relu(w1 @ h0 + c1)
                    float a1v = th[(4224 + l)*4 + b];
                    #pragma unroll
                    for (int k = 0; k < 64; ++k)
                        a1v += w1c[(k*64 + l)*4 + b] * __shfl(h0, k);
                    float h1 = fmaxf(a1v, 0.f);
                    // o = w2 @ h1 + c2  (32 outputs, lanes 0..31)
                    float ov = th[(6336 + (l & 31))*4 + b];
                    #pragma unroll
                    for (int k = 0; k < 64; ++k)
                        ov += w2c[(k*32 + (l & 31))*4 + b] * __shfl(h1, k);
                    if (l < 32) {
                        xv = (l < 16) ? tanhf(ov) : softplusf(ov);
                        outp[(b*T_STEPS + t)*32 + l] = xv;
                    }
                }
                if (it + 1 <= T_STEPS - 1) {
                    float* dd = diffb + ((it + 1) & 1) * 68 + b*17;
                    if (l < 16) {
                        float xprev = (it >= 1) ? xv : xs[(size_t)(b*T_STEPS)*16 + l];
                        dd[1 + l] = xs[(size_t)(b*T_STEPS + it + 1)*16 + l] - xprev;
                    } else if (l == 16) {
                        dd[0] = ts[b*T_STEPS + it + 1] - ts[b*T_STEPS + it];
                    }
                }
            }
            if (it < T_STEPS) grid_barrier(bar, (unsigned)(NBLK * (it + 1)));
        }
    }
}

// h1 = relu(W1 @ xs0 + b1), plus zero diff slots and barrier counter
__global__ __launch_bounds__(256)
void init_h1(const float* __restrict__ xs, const float* __restrict__ W1,
             const float* __restrict__ b1, float* __restrict__ h1ws,
             float* __restrict__ diffb)
{
    const int b = blockIdx.y;
    const int r = blockIdx.x * 256 + threadIdx.x;
    if (blockIdx.x == 0 && b == 0 && threadIdx.x < 137)
        diffb[threadIdx.x] = 0.f;  // 136 diff floats + barrier counter (bit pattern 0)
    if (r < H1_DIM) {
        const float* wr = W1 + r*16;
        const float* x0 = xs + (size_t)b * T_STEPS * 16;
        float s = b1[r];
        #pragma unroll
        for (int k = 0; k < 16; ++k) s += wr[k] * x0[k];
        h1ws[b*H1_DIM + r] = fmaxf(s, 0.f);
    }
}

// out[b][r] = maybe_relu(sum_k W[r][k]*in[b][k] + bias[r]); ilv => out[r*4+b]
__global__ __launch_bounds__(256)
void init_mm(const float* __restrict__ W, const float* __restrict__ bias,
             const float* __restrict__ in, float* __restrict__ outp,
             int rows, int K, int dorelu, int ilv)
{
    const int w = threadIdx.x >> 6, l = threadIdx.x & 63;
    const int gw = blockIdx.x * 4 + w;
    const int nw = gridDim.x * 4;
    for (int r = gw; r < rows; r += nw) {
        const float* wr = W + (size_t)r * K;
        float a0 = 0.f, a1 = 0.f, a2 = 0.f, a3 = 0.f;
        for (int k = l; k < K; k += 64) {
            float wv = wr[k];
            a0 += wv * in[k];
            a1 += wv * in[K + k];
            a2 += wv * in[2*K + k];
            a3 += wv * in[3*K + k];
        }
        #pragma unroll
        for (int off = 32; off; off >>= 1) {
            a0 += __shfl_xor(a0, off);
            a1 += __shfl_xor(a1, off);
            a2 += __shfl_xor(a2, off);
            a3 += __shfl_xor(a3, off);
        }
        if (l == 0) {
            float bb = bias[r];
            a0 += bb; a1 += bb; a2 += bb; a3 += bb;
            if (dorelu) {
                a0 = fmaxf(a0, 0.f); a1 = fmaxf(a1, 0.f);
                a2 = fmaxf(a2, 0.f); a3 = fmaxf(a3, 0.f);
            }
            if (ilv) {
                outp[r*4 + 0] = a0; outp[r*4 + 1] = a1;
                outp[r*4 + 2] = a2; outp[r*4 + 3] = a3;
            } else {
                outp[0*rows + r] = a0; outp[1*rows + r] = a1;
                outp[2*rows + r] = a2; outp[3*rows + r] = a3;
            }
        }
    }
}

extern "C" void kernel_launch(void* const* d_in, const int* in_sizes, int n_in,
                              void* d_out, int out_size, void* d_ws, size_t ws_size,
                              hipStream_t stream) {
    const float* xs = (const float*)d_in[0];
    const float* ts = (const float*)d_in[1];
    const float* A  = (const float*)d_in[2];
    const float* Bm = (const float*)d_in[3];
    const float* W1 = (const float*)d_in[4];
    const float* b1 = (const float*)d_in[5];
    const float* W2 = (const float*)d_in[6];
    const float* b2 = (const float*)d_in[7];
    const float* W3 = (const float*)d_in[8];
    const float* b3 = (const float*)d_in[9];
    // d_in[10] = seed: unused (FORCING_PROB == 1.0 makes the RNG dead code)
    float* outp = (float*)d_out;
    float* wsf  = (float*)d_ws;

    float* thetaA = wsf + OFF_THA;
    float* thetaB = wsf + OFF_THB;
    float* w1t    = wsf + OFF_W1T;
    float* w2t    = wsf + OFF_W2T;
    float* diffb  = wsf + OFF_DIFF;
    unsigned* bar = (unsigned*)(wsf + OFF_BAR);
    float* h1ws   = wsf + OFF_H1;
    float* h2ws   = wsf + OFF_H2;

    init_h1<<<dim3((H1_DIM + 255)/256, B_SZ), 256, 0, stream>>>(xs, W1, b1, h1ws, diffb);
    init_mm<<<dim3(128), 256, 0, stream>>>(W2, b2, h1ws, h2ws, H2_DIM, H1_DIM, 1, 0);
    init_mm<<<dim3(256), 256, 0, stream>>>(W3, b3, h2ws, thetaA, L_DIM, H2_DIM, 0, 1);
    seq_kernel<<<dim3(NBLK), dim3(512), 0, stream>>>(A, Bm, xs, ts, outp,
                                                     thetaA, thetaB, w1t, w2t, diffb, bar);
}